// Round 8
// baseline (378.075 us; speedup 1.0000x reference)
//
#include <hip/hip_runtime.h>
#include <cfloat>

#define N_Q     65536
#define D_DIM   256
#define K_CODES 1024
#define DELTA   0.004f
#define MARGIN  0.001f
#define SW_CAP  3072
#define SPILL_CAP 65536

// output float offsets (tuple concatenated flat, all as float32)
#define OUT_QST   0
#define OUT_LOSS  16777216
#define OUT_IDX   16777217
#define OUT_EMBED 16842753
#define OUT_COUNT 17104897
#define OUT_EMAW  17105921

// workspace byte offsets
#define WS_IDX    0u         // 65536*4: spill pool during sweep, idx after
#define WS_ZZ     262144u    // 65536*4 float ||z||^2 (written by sweep prologue)
#define WS_PERM   524288u    // 65536*4 int CSR permutation
#define WS_PACK   786432u    // 65536*8 uint64 packed (dist,idx), init by prep
#define WS_EN     1310720u   // 1024*4 float ||e||^2
#define WS_ICNT   1314816u   // 1024*4 int counts, zeroed by prep
#define WS_OFFS   1318912u   // 1024*4 int CSR offsets
#define WS_OFFW   1323008u   // 1024*4 int CSR fill cursor
#define WS_CNTF   1327104u   // 1024*4 float counts
#define WS_CS     1331200u   // 1024*4 float laplace-smoothed counts
#define WS_ET     1335296u   // 1024*256*2 bf16 embed in 32x32x16 A/B frag layout
#define WS_LOSSB  1859584u   // 1024*8 double loss buckets, zeroed by prep
#define WS_SPCNT  1867776u   // 4 B spill counter, zeroed by prep

typedef short          bf16x8 __attribute__((ext_vector_type(8)));
typedef unsigned short u16x8  __attribute__((ext_vector_type(8)));
typedef float          f32x16 __attribute__((ext_vector_type(16)));

__device__ inline unsigned short f2bf(float x) {   // RNE fp32 -> bf16
    unsigned u = __float_as_uint(x);
    u += 0x7FFFu + ((u >> 16) & 1u);
    return (unsigned short)(u >> 16);
}
__device__ inline float bf2f(unsigned short h) {
    return __uint_as_float((unsigned)h << 16);
}
__device__ inline u16x8 pack8(float4 a, float4 b) {
    u16x8 p;
    p[0]=f2bf(a.x); p[1]=f2bf(a.y); p[2]=f2bf(a.z); p[3]=f2bf(a.w);
    p[4]=f2bf(b.x); p[5]=f2bf(b.y); p[6]=f2bf(b.z); p[7]=f2bf(b.w);
    return p;
}
// async global->LDS, 16B per lane; lds dest is wave-uniform base + lane*16
__device__ inline void gll16(const void* g, void* l) {
    __builtin_amdgcn_global_load_lds(
        (const __attribute__((address_space(1))) unsigned int*)g,
        (__attribute__((address_space(3))) unsigned int*)l, 16, 0, 0);
}
// min with a DPP lane-permuted partner (VALU pipe). Row-confined (16-lane
// rows): 0xB1=quad_perm xor1, 0x4E=quad_perm xor2, 0x124=row_ror:4,
// 0x128=row_ror:8. Together: min over each 16-lane row. Fail-safe: any
// outcome is a min over a subset of one query's codes => threshold >= true
// => push set superset. (validated in r7)
#define DPPMIN(x, CTRL) fminf((x), __int_as_float( \
    __builtin_amdgcn_update_dpp(0, __float_as_int(x), (CTRL), 0xF, 0xF, false)))

// ---------------------------------------------------------------------------
// fused prep: conv_e + pack init (blocks 0..127), ||e||^2 + counter zeroing
// (blocks 128..159). conv_e emits the 32x32x16 MFMA B-operand fragment
// layout: group g (32 codes), kstep s (16 dims):
//   et[(g*16 + s)*512 + lane*8 + j] = bf16(E[g*32 + (lane&31)][s*16 + (lane>>5)*8 + j])
// so chunk g is 16 KB contiguous, staged linearly; a wave's B frag for kstep
// s is one ds_read_b128 at s*1024 + lane*16 bytes.
__global__ void prep_kernel(const float* __restrict__ embed,
                            unsigned short* __restrict__ et,
                            unsigned long long* __restrict__ pack,
                            float* __restrict__ enorm,
                            int* __restrict__ icnt,
                            double* __restrict__ lossb,
                            int* __restrict__ spc)
{
    int b = blockIdx.x, t = threadIdx.x;
    if (b < 128) {
        int tid = b * 256 + t;                        // 32768 threads
        int g = tid >> 10, rem = tid & 1023;
        int s = rem >> 6, lane = rem & 63;
        int row = g * 32 + (lane & 31);
        int d0  = s * 16 + (lane >> 5) * 8;
        const float* src = &embed[(size_t)row * D_DIM + d0];
        float4 a = *(const float4*)&src[0];
        float4 c = *(const float4*)&src[4];
        *(u16x8*)&et[(size_t)tid * 8] = pack8(a, c);
        // pack init (0xFF..): 16 B per thread covers 65536*8 B
        unsigned long long* p = pack + (size_t)tid * 2;
        p[0] = ~0ull; p[1] = ~0ull;
    } else {
        int b2 = b - 128;                             // 0..31
        int wave = t >> 6, lane = t & 63;
        int rbase = (b2 * 4 + wave) * 8;              // 8 rows per wave
        for (int i = 0; i < 8; ++i) {
            int r = rbase + i;
            const float4 v = *(const float4*)&embed[(size_t)r * D_DIM + lane * 4];
            float s = v.x * v.x + v.y * v.y + v.z * v.z + v.w * v.w;
            #pragma unroll
            for (int m = 32; m >= 1; m >>= 1) s += __shfl_down(s, m, 64);
            if (lane == 0) enorm[r] = s;
        }
        if (b2 == 0) {
            #pragma unroll
            for (int i = 0; i < 4; ++i) {
                icnt[t * 4 + i] = 0;
                lossb[t * 4 + i] = 0.0;
            }
            if (t == 0) *spc = 0;
        }
    }
}

// ---------------------------------------------------------------------------
// 32x32x16-MFMA sweep with 2-set codebook split:
//   - grid 512 = 2 sets x 256 query-blocks, 512 threads (8 waves). Block:
//     256 queries x 512 codes (16 chunks of 32 codes). Blocks bid and
//     bid+256 share queries and land on the same XCD (%8) -> z L2-shared.
//   - wave holds 32 queries as A fragments Aq[16] (64 VGPR, built once from
//     global z, fused ||z||^2) and ONE f32x16 accumulator. Each B fragment
//     (1 ds_read_b128) feeds a 32-query MFMA -> total ds_read_b128 and
//     staging volume HALVE vs the r7 structure (its measured tall pole).
//   - per chunk: issue next chunk's 16 KB staging (2 gll16/wave, dbuf),
//     16 ds_read + 16 MFMA, s1 in place (en is per-lane scalar: col=code),
//     16 DPP row-min chains (16-lane partial min -> fail-safe superset
//     thresholds), compact push, then vmcnt(0) drain + s_barrier (drain is
//     ~free: L2 latency << chunk slack; also closes r4/r7's latent
//     staging-vs-ds_read race).
//   - D layout (HW-verified m74/m101): col=lane&31 -> code, row=(reg&3)+
//     8*(reg>>2)+4*(lane>>5) -> query. A/B: m/n=lane&31, k=(lane>>5)*8+j
//     (same convention family as the r7-validated 16x16 mapping).
//   - tail: true per-query min (one shfl_xor(16) per reg), re-filter vs
//     min+DELTA+MARGIN, exact double rescore, ref op order
//     fl(fl(zz-2dot)+en), packed u64 atomicMin merges sets, first-index ties.
__launch_bounds__(512, 4)
__global__ void sweep_kernel(const float* __restrict__ z,
                             const float* __restrict__ embed,
                             const unsigned short* __restrict__ et,
                             const float* __restrict__ enorm,
                             float* __restrict__ zzg,
                             unsigned long long* __restrict__ pack,
                             unsigned* __restrict__ spill,
                             int* __restrict__ spc)
{
    __shared__ unsigned short Eb[2][8192];     // 2 x 16 KB E chunk double buffer
    __shared__ unsigned list[SW_CAP];          // 12 KB candidate entries
    __shared__ unsigned short s1h[SW_CAP];     //  6 KB bf16(s1) per entry
    __shared__ float Ens[512];                 //  2 KB ||e||^2 (this set)
    __shared__ float rminS[256];               // final per-query set-min
    __shared__ float zzS[256];                 // ||z||^2 for this block
    __shared__ int lcnt;

    const int t = threadIdx.x;
    const int w = t >> 6, lane = t & 63;       // 8 waves
    const int c32 = lane & 31, hi = lane >> 5;
    const int set = blockIdx.x >> 8;
    const int qb  = blockIdx.x & 255;
    const int qbase = qb * 256;
    const int koff  = set * 512;

    if (t == 0) lcnt = 0;
    Ens[t] = enorm[koff + t];                  // 512 threads cover 512 codes

    // stage chunk 0: 16 KB, wave w covers shorts [w*1024, +1024)
    {
        const unsigned short* src = et + (size_t)(set*16 + 0) * 8192 + w*1024 + lane*8;
        unsigned short* dst = &Eb[0][w * 1024];
        gll16(src, dst);
        gll16(src + 512, dst + 512);
    }

    // A fragments (32 queries) direct from global z + fused ||z||^2.
    // lane holds query row (lane&31), dims {s*16 + hi*8 .. +8} per frag s.
    bf16x8 Aq[16];
    {
        const float* zrow = &z[(size_t)(qbase + w*32 + c32) * D_DIM + hi*8];
        float s2 = 0.f;
        #pragma unroll
        for (int s = 0; s < 16; ++s) {
            float4 a = *(const float4*)&zrow[s*16];
            float4 b = *(const float4*)&zrow[s*16 + 4];
            s2 += a.x*a.x + a.y*a.y + a.z*a.z + a.w*a.w
                + b.x*b.x + b.y*b.y + b.z*b.z + b.w*b.w;
            u16x8 p = pack8(a, b);
            Aq[s] = *(bf16x8*)&p;
        }
        float zz = s2 + __shfl_xor(s2, 32, 64);   // partner has other dim-half
        if (lane < 32) {
            zzS[w*32 + c32] = zz;
            if (set == 0) zzg[qbase + w*32 + c32] = zz;
        }
    }

    float rmin[16];       // running per-(reg,row-half) partial min
    #pragma unroll
    for (int r = 0; r < 16; ++r) rmin[r] = FLT_MAX;

    // prologue sync: full drain (chunk-0 staging + Ens/zzS LDS writes)
    asm volatile("s_waitcnt vmcnt(0) lgkmcnt(0)" ::: "memory");
    __builtin_amdgcn_s_barrier();
    __builtin_amdgcn_sched_barrier(0);

    #pragma unroll 1
    for (int kc = 0; kc < 16; ++kc) {
        // issue next chunk's staging (hides under this chunk's compute)
        if (kc < 15) {
            const unsigned short* src =
                et + (size_t)(set*16 + kc + 1) * 8192 + w*1024 + lane*8;
            unsigned short* dst = &Eb[(kc + 1) & 1][w * 1024];
            gll16(src, dst);
            gll16(src + 512, dst + 512);
        }

        const unsigned short* buf = Eb[kc & 1];
        f32x16 acc;
        #pragma unroll
        for (int i = 0; i < 16; ++i) acc[i] = 0.f;

        #pragma unroll
        for (int s = 0; s < 16; ++s) {
            bf16x8 B = *(const bf16x8*)&buf[s*512 + lane*8];
            acc = __builtin_amdgcn_mfma_f32_32x32x16_bf16(Aq[s], B, acc, 0, 0, 0);
        }

        // s1 = ||e||^2 - 2*dot in place; en is a single per-lane scalar
        float en = Ens[kc*32 + c32];
        acc = en - 2.0f * acc;

        // per-reg (query) partial min over this 16-lane row's codes (DPP),
        // running min, threshold, compact push
        #pragma unroll
        for (int r = 0; r < 16; ++r) {
            float mv = acc[r];
            mv = DPPMIN(mv, 0xB1);    // xor1
            mv = DPPMIN(mv, 0x4E);    // xor2
            mv = DPPMIN(mv, 0x124);   // ror:4
            mv = DPPMIN(mv, 0x128);   // ror:8  -> min over 16-lane row
            rmin[r] = fminf(rmin[r], mv);
            float th = rmin[r] + DELTA;
            if (acc[r] <= th) {
                int k    = koff + kc*32 + c32;
                int qloc = w*32 + (r & 3) + 8*(r >> 2) + 4*hi;
                int pos  = atomicAdd(&lcnt, 1);
                if (pos < SW_CAP) {
                    list[pos] = ((unsigned)qloc << 10) | (unsigned)k;
                    s1h[pos]  = f2bf(acc[r]);
                } else {
                    int sp = atomicAdd(spc, 1);
                    if (sp < SPILL_CAP) {
                        spill[sp] = ((unsigned)(qbase + qloc) << 10)
                                  | (unsigned)k;
                        asm volatile("s_waitcnt vmcnt(0)" ::: "memory");
                    }
                }
            }
        }

        // full drain: staged loads had a chunk of slack (L2-resident) so
        // this retires ~free, and the next buffer is guaranteed complete.
        asm volatile("s_waitcnt vmcnt(0)" ::: "memory");
        __builtin_amdgcn_s_barrier();
        __builtin_amdgcn_sched_barrier(0);
    }

    // true per-query set-min: combine the two 16-lane rows of each half,
    // then publish (lane 0 -> hi=0 queries, lane 32 -> hi=1 queries)
    #pragma unroll
    for (int r = 0; r < 16; ++r)
        rmin[r] = fminf(rmin[r], __shfl_xor(rmin[r], 16, 64));
    if (c32 == 0) {
        #pragma unroll
        for (int r = 0; r < 16; ++r)
            rminS[w*32 + (r & 3) + 8*(r >> 2) + 4*hi] = rmin[r];
    }
    asm volatile("s_waitcnt lgkmcnt(0)" ::: "memory");
    __builtin_amdgcn_s_barrier();
    __builtin_amdgcn_sched_barrier(0);

    // exact rescore of candidates: 8-lane group per entry, lane covers 32 d;
    // skip entries whose stored bf16(s1) exceeds FINAL set-min + DELTA+MARGIN
    int cnt = lcnt; if (cnt > SW_CAP) cnt = SW_CAP;
    int gid = t >> 3, gl = t & 7;          // 64 groups of 8 lanes
    for (int e = gid; e < cnt; e += 64) {
        unsigned ent = list[e];
        int qloc = (int)(ent >> 10), k = (int)(ent & 1023u);
        if (bf2f(s1h[e]) > rminS[qloc] + (DELTA + MARGIN)) continue;
        int qg = qbase + qloc;
        const float* zp  = &z[(size_t)qg * D_DIM + gl * 32];
        const float* epf = &embed[(size_t)k * D_DIM + gl * 32];
        double d0 = 0.0, d1 = 0.0;
        #pragma unroll
        for (int i = 0; i < 4; ++i) {
            float4 a  = *(const float4*)&zp[i*8];
            float4 b  = *(const float4*)&epf[i*8];
            float4 c  = *(const float4*)&zp[i*8 + 4];
            float4 dv = *(const float4*)&epf[i*8 + 4];
            d0 += (double)a.x*b.x + (double)a.y*b.y + (double)a.z*b.z + (double)a.w*b.w;
            d1 += (double)c.x*dv.x + (double)c.y*dv.y + (double)c.z*dv.z + (double)c.w*dv.w;
        }
        double dd = d0 + d1;
        #pragma unroll
        for (int m = 1; m < 8; m <<= 1) dd += __shfl_xor(dd, m, 64);
        if (gl == 0) {
            float s = (zzS[qloc] - 2.0f*(float)dd) + Ens[k & 511];  // ref op order
            unsigned long long pk =
                ((unsigned long long)__float_as_uint(s) << 32) | (unsigned)k;
            atomicMin(&pack[qg], pk);
        }
    }
}

// ---------------------------------------------------------------------------
// drain the spill pool (normally empty): exact rescore of overflow entries
__global__ void spill_kernel(const float* __restrict__ z,
                             const float* __restrict__ embed,
                             const float* __restrict__ enorm,
                             const float* __restrict__ zz,
                             const unsigned* __restrict__ spill,
                             const int* __restrict__ spc,
                             unsigned long long* __restrict__ pack)
{
    int cnt = *spc; if (cnt > SPILL_CAP) cnt = SPILL_CAP;
    int gid = (blockIdx.x * 256 + threadIdx.x) >> 3, gl = threadIdx.x & 7;
    int stride = (gridDim.x * 256) >> 3;
    for (int e = gid; e < cnt; e += stride) {
        unsigned ent = spill[e];
        int qg = (int)(ent >> 10), k = (int)(ent & 1023u);
        const float* zp  = &z[(size_t)qg * D_DIM + gl * 32];
        const float* epf = &embed[(size_t)k * D_DIM + gl * 32];
        double dd = 0.0;
        #pragma unroll
        for (int i = 0; i < 8; ++i) {
            float4 a = *(const float4*)&zp[i*4];
            float4 b = *(const float4*)&epf[i*4];
            dd += (double)a.x*b.x + (double)a.y*b.y
                + (double)a.z*b.z + (double)a.w*b.w;
        }
        #pragma unroll
        for (int m = 1; m < 8; m <<= 1) dd += __shfl_xor(dd, m, 64);
        if (gl == 0) {
            float s = (zz[qg] - 2.0f*(float)dd) + enorm[k];
            unsigned long long pk =
                ((unsigned long long)__float_as_uint(s) << 32) | (unsigned)k;
            atomicMin(&pack[qg], pk);
        }
    }
}

// ---------------------------------------------------------------------------
// merged unpack + q_st + loss: per block 4 queries x 256 d. (validated r5/r7)
__global__ void qst_unpack_kernel(const unsigned long long* __restrict__ pack,
                                  const float* __restrict__ z,
                                  const float* __restrict__ embed,
                                  int* __restrict__ idx_i,
                                  float* __restrict__ idx_f,
                                  int* __restrict__ icnt,
                                  float* __restrict__ qst,
                                  double* __restrict__ lossb)
{
    __shared__ int ks[4];
    int b = blockIdx.x, t = threadIdx.x;
    int n0 = b * 4;
    if (t < 4) {
        int k = (int)(pack[n0 + t] & 0xffffffffull);
        ks[t] = k;
        idx_i[n0 + t] = k;
        idx_f[n0 + t] = (float)k;
        atomicAdd(&icnt[k], 1);
    }
    __syncthreads();
    int e0 = b * 1024 + t * 4;
    int qi = t >> 6;                   // query within block
    int d  = (t * 4) & 255;
    int k  = ks[qi];
    const float4 q4 = *(const float4*)&embed[(size_t)k * D_DIM + d];
    const float4 z4 = *(const float4*)&z[e0];
    float4 o;
    o.x = z4.x + (q4.x - z4.x);
    o.y = z4.y + (q4.y - z4.y);
    o.z = z4.z + (q4.z - z4.z);
    o.w = z4.w + (q4.w - z4.w);
    *(float4*)&qst[e0] = o;
    float dx = z4.x - q4.x, dy = z4.y - q4.y, dz = z4.z - q4.z, dw = z4.w - q4.w;
    float s = dx * dx + dy * dy + dz * dz + dw * dw;
    #pragma unroll
    for (int m = 32; m >= 1; m >>= 1) s += __shfl_down(s, m, 64);
    __shared__ float ps[4];
    int wave = t >> 6, lane = t & 63;
    if (lane == 0) ps[wave] = s;
    __syncthreads();
    if (t == 0)
        atomicAdd(&lossb[b & 1023],
                  (double)((ps[0] + ps[1]) + (ps[2] + ps[3])));
}

// ---------------------------------------------------------------------------
// exclusive scan of counts (1 block x 1024) -> offsets + fill cursor + float counts
__global__ void scan_kernel(const int* __restrict__ icnt,
                            int* __restrict__ offs,
                            int* __restrict__ offw,
                            float* __restrict__ cntf)
{
    __shared__ int s[1024];
    int t = threadIdx.x;
    int v0 = icnt[t];
    s[t] = v0;
    __syncthreads();
    for (int d = 1; d < 1024; d <<= 1) {
        int v = (t >= d) ? s[t - d] : 0;
        __syncthreads();
        s[t] += v;
        __syncthreads();
    }
    int excl = s[t] - v0;
    offs[t] = excl;
    offw[t] = excl;
    cntf[t] = (float)v0;
}

// ---------------------------------------------------------------------------
// build CSR permutation (order within a code arbitrary; accum uses double)
__global__ void fill_kernel(const int* __restrict__ idx,
                            int* __restrict__ offw,
                            int* __restrict__ perm)
{
    int n = blockIdx.x * 256 + threadIdx.x;
    int k = idx[n];
    int pos = atomicAdd(&offw[k], 1);
    perm[pos] = n;
}

// ---------------------------------------------------------------------------
// new_count, n = sum(new_count), cs, vq_loss finalize (single block of 1024)
__global__ void fin_counts_kernel(const float* __restrict__ ema_count,
                                  const float* __restrict__ cntf,
                                  const double* __restrict__ lossb,
                                  float* __restrict__ out_count,
                                  float* __restrict__ out_loss,
                                  float* __restrict__ cs)
{
    __shared__ float  red[1024];
    __shared__ double dred[1024];
    int t = threadIdx.x;
    float c = 0.99f * ema_count[t] + 0.01f * cntf[t];
    out_count[t] = c;
    red[t]  = c;
    dred[t] = lossb[t];
    __syncthreads();
    for (int s = 512; s >= 1; s >>= 1) {
        if (t < s) { red[t] += red[t + s]; dred[t] += dred[t + s]; }
        __syncthreads();
    }
    float n = red[0];
    cs[t] = (c + 1e-5f) / (n + 1024.0f * 1e-5f) * n;
    if (t == 0) {
        float m = (float)(dred[0] / (double)((size_t)N_Q * D_DIM));
        out_loss[0] = m + 0.25f * m;   // codebook + BETA*commit, bitwise equal halves
    }
}

// ---------------------------------------------------------------------------
// per-code: dw[k,d] = sum over members of z (double accum, 4-way ILP), then
// EMA + normalize. One block per code; thread t handles column d=t.
__global__ void accum_embed_kernel(const float* __restrict__ z,
                                   const int* __restrict__ perm,
                                   const int* __restrict__ icnt,
                                   const int* __restrict__ offs,
                                   const float* __restrict__ cs,
                                   const float* __restrict__ ema_w,
                                   float* __restrict__ out_embed,
                                   float* __restrict__ out_emaw)
{
    __shared__ int rows[256];
    int k = blockIdx.x, t = threadIdx.x;
    int cnt = icnt[k], off = offs[k];
    double a0 = 0.0, a1 = 0.0, a2 = 0.0, a3 = 0.0;
    for (int base = 0; base < cnt; base += 256) {
        int m = min(256, cnt - base);
        __syncthreads();
        if (t < m) rows[t] = perm[off + base + t];
        __syncthreads();
        int r = 0;
        for (; r + 4 <= m; r += 4) {
            a0 += (double)z[(size_t)rows[r+0] * D_DIM + t];
            a1 += (double)z[(size_t)rows[r+1] * D_DIM + t];
            a2 += (double)z[(size_t)rows[r+2] * D_DIM + t];
            a3 += (double)z[(size_t)rows[r+3] * D_DIM + t];
        }
        for (; r < m; ++r) a0 += (double)z[(size_t)rows[r] * D_DIM + t];
    }
    double acc = (a0 + a1) + (a2 + a3);
    float w = 0.99f * ema_w[(size_t)k * D_DIM + t] + 0.01f * (float)acc;
    out_emaw[(size_t)k * D_DIM + t]  = w;
    out_embed[(size_t)k * D_DIM + t] = w / cs[k];
}

// ---------------------------------------------------------------------------
extern "C" void kernel_launch(void* const* d_in, const int* in_sizes, int n_in,
                              void* d_out, int out_size, void* d_ws, size_t ws_size,
                              hipStream_t stream)
{
    const float* z          = (const float*)d_in[0];
    const float* embed      = (const float*)d_in[1];
    const float* ema_count  = (const float*)d_in[2];
    const float* ema_weight = (const float*)d_in[3];
    float* out = (float*)d_out;
    char*  ws  = (char*)d_ws;

    int*      ws_idx  = (int*)(ws + WS_IDX);
    unsigned* ws_spill= (unsigned*)(ws + WS_IDX);   // aliased: free during sweep
    float*    ws_zz   = (float*)(ws + WS_ZZ);
    int*      ws_perm = (int*)(ws + WS_PERM);
    unsigned long long* ws_pack = (unsigned long long*)(ws + WS_PACK);
    float*    ws_en   = (float*)(ws + WS_EN);
    int*      ws_icnt = (int*)(ws + WS_ICNT);
    int*      ws_offs = (int*)(ws + WS_OFFS);
    int*      ws_offw = (int*)(ws + WS_OFFW);
    float*    ws_cntf = (float*)(ws + WS_CNTF);
    float*    ws_cs   = (float*)(ws + WS_CS);
    unsigned short* ws_et = (unsigned short*)(ws + WS_ET);
    double*   ws_lb   = (double*)(ws + WS_LOSSB);
    int*      ws_spc  = (int*)(ws + WS_SPCNT);

    prep_kernel<<<160, 256, 0, stream>>>(embed, ws_et, ws_pack, ws_en,
                                         ws_icnt, ws_lb, ws_spc);

    sweep_kernel<<<512, 512, 0, stream>>>(z, embed, ws_et, ws_en, ws_zz,
                                          ws_pack, ws_spill, ws_spc);

    spill_kernel<<<32, 256, 0, stream>>>(z, embed, ws_en, ws_zz,
                                         ws_spill, ws_spc, ws_pack);

    qst_unpack_kernel<<<N_Q / 4, 256, 0, stream>>>(ws_pack, z, embed,
                                                   ws_idx, out + OUT_IDX,
                                                   ws_icnt, out + OUT_QST, ws_lb);
    scan_kernel<<<1, 1024, 0, stream>>>(ws_icnt, ws_offs, ws_offw, ws_cntf);
    fill_kernel<<<N_Q / 256, 256, 0, stream>>>(ws_idx, ws_offw, ws_perm);
    fin_counts_kernel<<<1, 1024, 0, stream>>>(ema_count, ws_cntf, ws_lb,
                                              out + OUT_COUNT, out + OUT_LOSS, ws_cs);
    accum_embed_kernel<<<K_CODES, 256, 0, stream>>>(z, ws_perm, ws_icnt, ws_offs,
                                                    ws_cs, ema_weight,
                                                    out + OUT_EMBED, out + OUT_EMAW);
}